// Round 1
// baseline (99.535 us; speedup 1.0000x reference)
//
#include <hip/hip_runtime.h>
#include <math.h>

// ---- Problem constants (baked into the reference) ----
#define NATOM 4096
#define KX 14
#define KY 15
#define KZ 16
#define SLAB (KY*KZ)              // 240
#define NGRID (KX*SLAB)           // 3360
#define NB 128                    // spread blocks
#define APB (NATOM/NB)            // 32 atoms per spread block
#define NTRI 544                  // triangular direct tiles: sum_{ci<16}(64-4ci)

static constexpr float ALPHA_F   = 4.985823141035867f;
static constexpr float COULOMB_F = 138.935f;
static constexpr float CUT2_F    = 0.25f;    // CUTOFF^2
static constexpr float TWOPI_F   = 6.283185307179586f;
static constexpr float PI_F      = 3.14159265358979f;

#define POIS32 0xAAAAAAAAu        // ws poison pattern (verified prior session)
#define SPREAD_LAST (POIS32 + 127u)   // fetch_add old value for the 128th spread block
#define DONE_LAST   (POIS32 + 544u)   // 544 direct blocks + 1 recip completion = 545 bumps

// ---- Cardinal B-spline M5 via the Essmann recursion (matches reference _M) ----
__device__ __forceinline__ float M1f(float x){ return (x >= 0.f && x < 1.f) ? 1.f : 0.f; }
__device__ __forceinline__ float M2f(float x){ return x*M1f(x) + (2.f-x)*M1f(x-1.f); }
__device__ __forceinline__ float M3f(float x){ return (x*M2f(x) + (3.f-x)*M2f(x-1.f)) * 0.5f; }
__device__ __forceinline__ float M4f(float x){ return (x*M3f(x) + (4.f-x)*M3f(x-1.f)) * (1.f/3.f); }
__device__ __forceinline__ float M5f(float x){ return (x*M4f(x) + (5.f-x)*M4f(x-1.f)) * 0.25f; }

__device__ __forceinline__ void inv3x3(const float* b, float* inv){
  float det = b[0]*(b[4]*b[8]-b[5]*b[7]) - b[1]*(b[3]*b[8]-b[5]*b[6]) + b[2]*(b[3]*b[7]-b[4]*b[6]);
  float id = 1.f/det;
  inv[0] = (b[4]*b[8]-b[5]*b[7])*id;
  inv[1] = (b[2]*b[7]-b[1]*b[8])*id;
  inv[2] = (b[1]*b[5]-b[2]*b[4])*id;
  inv[3] = (b[5]*b[6]-b[3]*b[8])*id;
  inv[4] = (b[0]*b[8]-b[2]*b[6])*id;
  inv[5] = (b[2]*b[3]-b[0]*b[5])*id;
  inv[6] = (b[3]*b[7]-b[4]*b[6])*id;
  inv[7] = (b[1]*b[6]-b[0]*b[7])*id;
  inv[8] = (b[0]*b[4]-b[1]*b[3])*id;
}

// |b(m)|^-2 ; M5 at integers 1..4 = {1,11,11,1}/24; exact zeros at odd-order m=K/2
__device__ __forceinline__ float bmod(int m, int K){
  float base = TWOPI_F * (float)m / (float)K;
  float s, c;
  float dr = 1.f/24.f, di = 0.f;
  __sincosf(base,      &s, &c); dr += (11.f/24.f)*c; di += (11.f/24.f)*s;
  __sincosf(base*2.f,  &s, &c); dr += (11.f/24.f)*c; di += (11.f/24.f)*s;
  __sincosf(base*3.f,  &s, &c); dr += (1.f/24.f)*c;  di += (1.f/24.f)*s;
  float d2 = dr*dr + di*di;
  return (d2 < 1e-7f) ? 0.f : 1.f/d2;
}

// erfc(x) = poly(t)*exp(-x^2), t=1/(1+p x)  (A&S 7.1.26, |e|<1.5e-7); exp applied by caller
__device__ __forceinline__ float erfc_poly(float x){
  float tt = __builtin_amdgcn_rcpf(1.f + 0.3275911f*x);
  return ((((1.061405429f*tt - 1.453152027f)*tt + 1.421413741f)*tt
          - 0.284496736f)*tt + 0.254829592f)*tt;
}

// ---- final combine: sums dpart + q^2, reads acc_rec, writes out[0] ----
__device__ __forceinline__ void final_combine(int t, const float* __restrict__ chg,
    const float* __restrict__ box, const double* __restrict__ dpart,
    double* __restrict__ acc_rec, float* __restrict__ out, double* red)
{
  int lane = t & 63, wid = t >> 6;
  double s_dir = __hip_atomic_load(&dpart[t],     __ATOMIC_RELAXED, __HIP_MEMORY_SCOPE_AGENT)
               + __hip_atomic_load(&dpart[t+256], __ATOMIC_RELAXED, __HIP_MEMORY_SCOPE_AGENT)
               + ((t < NTRI-512)
                  ? __hip_atomic_load(&dpart[t+512], __ATOMIC_RELAXED, __HIP_MEMORY_SCOPE_AGENT)
                  : 0.0);
  double s_q2 = 0.0;
  #pragma unroll
  for (int i = t; i < NATOM; i += 256){ double q = (double)chg[i]; s_q2 += q*q; }
  #pragma unroll
  for (int off = 32; off > 0; off >>= 1){
    s_dir += __shfl_down(s_dir, off);
    s_q2  += __shfl_down(s_q2,  off);
  }
  if (lane == 0){ red[4+wid] = s_dir; red[8+wid] = s_q2; }
  __syncthreads();
  if (t == 0){
    double D = red[4]+red[5]+red[6]+red[7];
    double Q = red[8]+red[9]+red[10]+red[11];
    double R = __hip_atomic_load(acc_rec, __ATOMIC_ACQUIRE, __HIP_MEMORY_SCOPE_AGENT);
    // R includes f64-poison offset -3.7e-103: negligible
    double b00=box[0],b01=box[1],b02=box[2],
           b10=box[3],b11=box[4],b12=box[5],
           b20=box[6],b21=box[7],b22=box[8];
    double det = b00*(b11*b22 - b12*b21) - b01*(b10*b22 - b12*b20) + b02*(b10*b21 - b11*b20);
    double V = fabs(det);
    const double PI_D = 3.141592653589793238462643;
    double edir  = 0.5 * (double)COULOMB_F * D;
    double erec  = (double)COULOMB_F / (2.0*PI_D*V) * R;
    double eself = -(double)COULOMB_F * 4.985823141035867 / sqrt(PI_D) * Q;
    out[0] = (float)(edir - erec - eself);
  }
}

// ========== ONE fused kernel ==========
// blocks 0..543   : triangular direct tiles -> agent atomic store dpart[b] -> bump dctr
// blocks 544..671 : spread -> LDS mesh -> device-scope fold into grid -> bump sctr;
//                   the 128th folder runs the full 16-mz DFT inline (overlapped with
//                   direct tiles), adds to acc_rec, bumps dctr.
// last of 545 dctr bumps runs final_combine. Counter-gated; no spins; any dispatch order.
__global__ __launch_bounds__(256) void pme_kernel(const float* __restrict__ pos,
    const float* __restrict__ chg, const float* __restrict__ box,
    float* __restrict__ grid, double* __restrict__ dpart,
    double* __restrict__ acc_rec, unsigned* __restrict__ sctr,
    unsigned* __restrict__ dctr, float* __restrict__ out)
{
  __shared__ __align__(16) float sg[NGRID];   // spread mesh; recip tables aliased here
  __shared__ float4 sj[64];                   // direct j-tile (x,y,z,q)
  __shared__ double red[12];
  __shared__ float bmz[KZ];
  __shared__ int flag;
  int t = threadIdx.x;
  int b = blockIdx.x;

  if (b < NTRI){
    // -------- direct tile (ci,cj); off-diagonal tiles counted twice --------
    int rem = b, ci = 0;
    while (true){ int cnt = 64 - 4*ci; if (rem < cnt) break; rem -= cnt; ++ci; }
    int cj = 4*ci + rem;
    bool offdiag = (rem >= 4);
    int i  = ci*256 + t;
    int j0 = cj*64;
    if (t < 64){
      int j = j0 + t;
      sj[t] = make_float4(pos[j*3+0], pos[j*3+1], pos[j*3+2], chg[j]);
    }
    __syncthreads();

    float b00=box[0],b01=box[1],b02=box[2],
          b10=box[3],b11=box[4],b12=box[5],
          b20=box[6],b21=box[7],b22=box[8];
    bool diag = (b01==0.f && b02==0.f && b10==0.f && b12==0.f && b20==0.f && b21==0.f);
    float i00 = 1.f/b00, i11 = 1.f/b11, i22 = 1.f/b22;

    float xi = pos[i*3+0], yi = pos[i*3+1], zi = pos[i*3+2], qi = chg[i];
    const float A2 = ALPHA_F*ALPHA_F;
    float e = 0.f;

    if (diag){
      #pragma unroll 4
      for (int jj = 0; jj < 64; ++jj){
        float4 v = sj[jj];
        float dx = xi - v.x, dy = yi - v.y, dz = zi - v.z;
        dz -= b22*rintf(dz*i22);
        dy -= b11*rintf(dy*i11);
        dx -= b00*rintf(dx*i00);
        float r2 = dx*dx + dy*dy + dz*dz;
        // self-pair gives exactly r2==0 (dx=xi-xi=0, rint(0)=0) -> excluded by r2>0
        if (r2 < CUT2_F && r2 > 0.f){
          float rinv = __builtin_amdgcn_rsqf(r2);
          float x = ALPHA_F * (r2 * rinv);
          e += qi * v.w * erfc_poly(x) * __expf(-A2*r2) * rinv;
        }
      }
    } else {
      for (int jj = 0; jj < 64; ++jj){
        float4 v = sj[jj];
        float dx = xi - v.x, dy = yi - v.y, dz = zi - v.z;
        float t2 = rintf(dz * i22); dx -= b20*t2; dy -= b21*t2; dz -= b22*t2;
        float t1 = rintf(dy * i11); dx -= b10*t1; dy -= b11*t1; dz -= b12*t1;
        float t0 = rintf(dx * i00); dx -= b00*t0; dy -= b01*t0; dz -= b02*t0;
        float r2 = dx*dx + dy*dy + dz*dz;
        if (r2 < CUT2_F && r2 > 0.f){
          float rinv = __builtin_amdgcn_rsqf(r2);
          float x = ALPHA_F * (r2 * rinv);
          e += qi * v.w * erfc_poly(x) * __expf(-A2*r2) * rinv;
        }
      }
    }

    double de = (double)e;
    #pragma unroll
    for (int off = 32; off > 0; off >>= 1) de += __shfl_down(de, off);
    if ((t & 63) == 0) red[t >> 6] = de;
    __syncthreads();
    if (t == 0){
      double s = red[0]+red[1]+red[2]+red[3];
      s = offdiag ? 2.0*s : s;
      // agent-scope store: visible cross-XCD without a kernel boundary
      __hip_atomic_store(&dpart[b], s, __ATOMIC_RELAXED, __HIP_MEMORY_SCOPE_AGENT);
      asm volatile("s_waitcnt vmcnt(0)" ::: "memory");   // store retired before counter
      unsigned old = __hip_atomic_fetch_add(dctr, 1u, __ATOMIC_ACQ_REL, __HIP_MEMORY_SCOPE_AGENT);
      flag = (old == DONE_LAST) ? 1 : 0;
    }
    __syncthreads();
    if (flag) final_combine(t, chg, box, dpart, acc_rec, out, red);
    return;
  }

  // -------- spread: (atom,jx) split over 160 threads -> LDS mesh -> fold --------
  int sb = b - NTRI;
  for (int i = t; i < NGRID; i += 256) sg[i] = 0.f;
  __syncthreads();

  if (t < APB*5){
    int a   = t / 5;
    int jxi = t - 5*a;
    int atom = sb*APB + a;
    float bx[9], inv[9];
    #pragma unroll
    for (int i = 0; i < 9; ++i) bx[i] = box[i];
    inv3x3(bx, inv);

    float px = pos[atom*3+0], py = pos[atom*3+1], pz = pos[atom*3+2];
    float qi = chg[atom];
    float fr[3];
    fr[0] = px*inv[0] + py*inv[3] + pz*inv[6];
    fr[1] = px*inv[1] + py*inv[4] + pz*inv[7];
    fr[2] = px*inv[2] + py*inv[5] + pz*inv[8];

    const int Ks[3] = {KX, KY, KZ};
    float w[3][5]; int id[3][5];
    #pragma unroll
    for (int ax = 0; ax < 3; ++ax) {
      float f = fr[ax] - floorf(fr[ax]);
      float u = f * (float)Ks[ax];
      float bse = floorf(u);
      float x = u - bse;
      int bi = (int)bse;
      #pragma unroll
      for (int j = 0; j < 5; ++j) {
        w[ax][j] = M5f(x + (float)j);          // weight for grid point (base - j)
        int ii = bi - j; if (ii < 0) ii += Ks[ax];
        id[ax][j] = ii;
      }
    }
    float qx = qi * w[0][jxi];
    int ox = id[0][jxi]*SLAB;
    #pragma unroll
    for (int jy = 0; jy < 5; ++jy) {
      float qxy = qx * w[1][jy];
      int oxy = ox + id[1][jy]*KZ;
      #pragma unroll
      for (int jz = 0; jz < 5; ++jz)
        atomicAdd(&sg[oxy + id[2][jz]], qxy * w[2][jz]);
    }
  }
  __syncthreads();
  for (int i = t; i < NGRID; i += 256){
    float v = sg[i];
    if (v != 0.f) atomicAdd(&grid[i], v);      // device-scope fold into ONE mesh
  }
  __syncthreads();                              // all folds retired (vmcnt(0) per wave)
  if (t == 0){
    unsigned old = __hip_atomic_fetch_add(sctr, 1u, __ATOMIC_ACQ_REL, __HIP_MEMORY_SCOPE_AGENT);
    flag = (old == SPREAD_LAST) ? 1 : 0;
  }
  __syncthreads();
  if (!flag) return;

  // ======== recip (only the 128th-arriving spread block), all 16 mz planes ========
  // Tables aliased onto sg (mesh already folded; block passed a barrier since).
  float2* Tz = (float2*)sg;          // [mz][gz] 256
  float2* Ty = Tz + KZ*KZ;           // [my][gy] 225
  float2* Tx = Ty + KY*KY;           // [mx][gx] 196
  float2* Cz = Tx + KX*KX;           // [gx][gy] 210 (current mz)
  float2* Cy = Cz + KX*KY;           // [gx][my] 210  -> 1097 float2 = 8776 B < 13440 B

  if (t < KZ*KZ){
    int mz = t >> 4, gz = t & 15;
    float s, c; __sincosf(-TWOPI_F*(float)((mz*gz)&15)/(float)KZ, &s, &c);
    Tz[t] = make_float2(c, s);
  }
  if (t < KY*KY){
    int my = t / KY, gy = t % KY;
    float s, c; __sincosf(-TWOPI_F*(float)((my*gy)%KY)/(float)KY, &s, &c);
    Ty[t] = make_float2(c, s);
  }
  if (t < KX*KX){
    int mx = t / KX, gx = t % KX;
    float s, c; __sincosf(-TWOPI_F*(float)((mx*gx)%KX)/(float)KX, &s, &c);
    Tx[t] = make_float2(c, s);
  }
  if (t < KZ) bmz[t] = bmod(t, KZ);

  int u = t;                          // 0..209 active
  float q[KZ];
  float Bxy = 0.f, mv0b = 0.f, mv1b = 0.f, mv2b = 0.f, iz0 = 0.f, iz1 = 0.f, iz2 = 0.f;
  if (u < KX*KY){
    const float P = __uint_as_float(POIS32);    // grid cells = poison + folded sums
    #pragma unroll
    for (int k = 0; k < KZ; ++k)
      q[k] = __hip_atomic_load(&grid[u*KZ + k], __ATOMIC_RELAXED, __HIP_MEMORY_SCOPE_AGENT) - P;
    int mx = u / KY, my = u % KY;               // x-pass identity of this thread
    Bxy = bmod(mx,KX)*bmod(my,KY);
    float bx[9], inv[9];
    #pragma unroll
    for (int k = 0; k < 9; ++k) bx[k] = box[k];
    inv3x3(bx, inv);
    float fx = (mx <= (KX-1)/2) ? (float)mx : (float)(mx - KX);
    float fy = (my <= (KY-1)/2) ? (float)my : (float)(my - KY);
    mv0b = fx*inv[0] + fy*inv[1]; iz0 = inv[2];
    mv1b = fx*inv[3] + fy*inv[4]; iz1 = inv[5];
    mv2b = fx*inv[6] + fy*inv[7]; iz2 = inv[8];
  }
  int gx_y = u / KY, my_y = u % KY;   // y-pass identity
  __syncthreads();

  double s_rec = 0.0;
  for (int mz = 0; mz < KZ; ++mz){
    if (u < KX*KY){                   // z-DFT of this thread's z-column at mz
      float br = 0.f, bi = 0.f;
      #pragma unroll
      for (int gz = 0; gz < KZ; ++gz){
        float2 w = Tz[mz*KZ + gz];
        br += q[gz]*w.x; bi += q[gz]*w.y;
      }
      Cz[u] = make_float2(br, bi);
    }
    __syncthreads();
    if (u < KX*KY){                   // y-pass
      float ar = 0.f, ai = 0.f;
      #pragma unroll
      for (int gy = 0; gy < KY; ++gy){
        float2 v = Cz[gx_y*KY + gy];
        float2 w = Ty[my_y*KY + gy];
        ar += v.x*w.x - v.y*w.y;
        ai += v.x*w.y + v.y*w.x;
      }
      Cy[u] = make_float2(ar, ai);
    }
    __syncthreads();
    if (u < KX*KY){                   // x-pass + green
      int mx = u / KY, my = u % KY;
      float Fr = 0.f, Fi = 0.f;
      #pragma unroll
      for (int gx = 0; gx < KX; ++gx){
        float2 v = Cy[gx*KY + my];
        float2 w = Tx[mx*KX + gx];
        Fr += v.x*w.x - v.y*w.y;
        Fi += v.x*w.y + v.y*w.x;
      }
      float fz = (mz <= (KZ-1)/2) ? (float)mz : (float)(mz - KZ);
      float m0 = mv0b + fz*iz0;
      float m1 = mv1b + fz*iz1;
      float m2c = mv2b + fz*iz2;
      float m2 = m0*m0 + m1*m1 + m2c*m2c;
      float B  = Bxy * bmz[mz];
      if (m2 > 0.f && B > 0.f){
        float green = __expf(-(PI_F*PI_F)*m2/(ALPHA_F*ALPHA_F)) / m2;
        s_rec += (double)(green*B) * ((double)Fr*(double)Fr + (double)Fi*(double)Fi);
      }
    }
    __syncthreads();                  // Cy reads done before next iter's writes
  }

  #pragma unroll
  for (int off = 32; off > 0; off >>= 1) s_rec += __shfl_down(s_rec, off);
  int lane = t & 63, wid = t >> 6;
  if (lane == 0) red[wid] = s_rec;
  __syncthreads();
  if (t == 0){
    atomicAdd(acc_rec, red[0]+red[1]+red[2]+red[3]);   // f64, device-scope
    asm volatile("s_waitcnt vmcnt(0)" ::: "memory");   // acc add retired before counter
    unsigned old = __hip_atomic_fetch_add(dctr, 1u, __ATOMIC_ACQ_REL, __HIP_MEMORY_SCOPE_AGENT);
    flag = (old == DONE_LAST) ? 1 : 0;
  }
  __syncthreads();
  if (flag) final_combine(t, chg, box, dpart, acc_rec, out, red);
}

extern "C" void kernel_launch(void* const* d_in, const int* in_sizes, int n_in,
                              void* d_out, int out_size, void* d_ws, size_t ws_size,
                              hipStream_t stream) {
  const float* pos = (const float*)d_in[0];   // [4096,3] f32
  const float* chg = (const float*)d_in[1];   // [4096]   f32
  const float* box = (const float*)d_in[2];   // [3,3]    f32
  float* out = (float*)d_out;

  // ws layout (all fields start at 0xAA poison; schemes account for it)
  char* w = (char*)d_ws;
  float*    grid    = (float*)w;                    // 3360 f32 @ 0 (16B aligned)
  double*   dpart   = (double*)(w + 16384);         // 544 f64 (agent atomic store/load)
  double*   acc_rec = (double*)(w + 24576);         // 1 f64 (starts -3.7e-103)
  unsigned* sctr    = (unsigned*)(w + 24584);       // spread counter, starts POIS32
  unsigned* dctr    = (unsigned*)(w + 24588);       // done counter,   starts POIS32

  pme_kernel<<<NTRI + NB, 256, 0, stream>>>(pos, chg, box, grid, dpart,
                                            acc_rec, sctr, dctr, out);
}

// Round 2
// 94.345 us; speedup vs baseline: 1.0550x; 1.0550x over previous
//
#include <hip/hip_runtime.h>
#include <math.h>

// ---- Problem constants (baked into the reference) ----
#define NATOM 4096
#define KX 14
#define KY 15
#define KZ 16
#define SLAB (KY*KZ)              // 240
#define NGRID (KX*SLAB)           // 3360
#define NB 128                    // spread blocks
#define APB (NATOM/NB)            // 32 atoms per spread block
#define NTRI 544                  // triangular direct tiles: sum_{ci<16}(64-4ci)

static constexpr float ALPHA_F   = 4.985823141035867f;
static constexpr float COULOMB_F = 138.935f;
static constexpr float CUT2_F    = 0.25f;    // CUTOFF^2
static constexpr float TWOPI_F   = 6.283185307179586f;
static constexpr float PI_F      = 3.14159265358979f;

#define POIS32 0xAAAAAAAAu        // ws poison pattern (verified prior session)
#define SPREAD_LAST (POIS32 + 127u)   // fetch_add old value for the 128th spread block
#define DONE_LAST   (POIS32 + 544u)   // 544 direct blocks + 1 recip completion = 545 bumps

// ---- Cardinal B-spline M5 via the Essmann recursion (matches reference _M) ----
__device__ __forceinline__ float M1f(float x){ return (x >= 0.f && x < 1.f) ? 1.f : 0.f; }
__device__ __forceinline__ float M2f(float x){ return x*M1f(x) + (2.f-x)*M1f(x-1.f); }
__device__ __forceinline__ float M3f(float x){ return (x*M2f(x) + (3.f-x)*M2f(x-1.f)) * 0.5f; }
__device__ __forceinline__ float M4f(float x){ return (x*M3f(x) + (4.f-x)*M3f(x-1.f)) * (1.f/3.f); }
__device__ __forceinline__ float M5f(float x){ return (x*M4f(x) + (5.f-x)*M4f(x-1.f)) * 0.25f; }

__device__ __forceinline__ void inv3x3(const float* b, float* inv){
  float det = b[0]*(b[4]*b[8]-b[5]*b[7]) - b[1]*(b[3]*b[8]-b[5]*b[6]) + b[2]*(b[3]*b[7]-b[4]*b[6]);
  float id = 1.f/det;
  inv[0] = (b[4]*b[8]-b[5]*b[7])*id;
  inv[1] = (b[2]*b[7]-b[1]*b[8])*id;
  inv[2] = (b[1]*b[5]-b[2]*b[4])*id;
  inv[3] = (b[5]*b[6]-b[3]*b[8])*id;
  inv[4] = (b[0]*b[8]-b[2]*b[6])*id;
  inv[5] = (b[2]*b[3]-b[0]*b[5])*id;
  inv[6] = (b[3]*b[7]-b[4]*b[6])*id;
  inv[7] = (b[1]*b[6]-b[0]*b[7])*id;
  inv[8] = (b[0]*b[4]-b[1]*b[3])*id;
}

// |b(m)|^-2 ; M5 at integers 1..4 = {1,11,11,1}/24; exact zeros at odd-order m=K/2
__device__ __forceinline__ float bmod(int m, int K){
  float base = TWOPI_F * (float)m / (float)K;
  float s, c;
  float dr = 1.f/24.f, di = 0.f;
  __sincosf(base,      &s, &c); dr += (11.f/24.f)*c; di += (11.f/24.f)*s;
  __sincosf(base*2.f,  &s, &c); dr += (11.f/24.f)*c; di += (11.f/24.f)*s;
  __sincosf(base*3.f,  &s, &c); dr += (1.f/24.f)*c;  di += (1.f/24.f)*s;
  float d2 = dr*dr + di*di;
  return (d2 < 1e-7f) ? 0.f : 1.f/d2;
}

// erfc(x) = poly(t)*exp(-x^2), t=1/(1+p x)  (A&S 7.1.26, |e|<1.5e-7); exp applied by caller
__device__ __forceinline__ float erfc_poly(float x){
  float tt = __builtin_amdgcn_rcpf(1.f + 0.3275911f*x);
  return ((((1.061405429f*tt - 1.453152027f)*tt + 1.421413741f)*tt
          - 0.284496736f)*tt + 0.254829592f)*tt;
}

// ---- final combine: sums dpart + q^2, reads acc_rec, writes out[0] ----
__device__ __forceinline__ void final_combine(int t, const float* __restrict__ chg,
    const float* __restrict__ box, const double* __restrict__ dpart,
    double* __restrict__ acc_rec, float* __restrict__ out, double* red)
{
  int lane = t & 63, wid = t >> 6;
  double s_dir = __hip_atomic_load(&dpart[t],     __ATOMIC_RELAXED, __HIP_MEMORY_SCOPE_AGENT)
               + __hip_atomic_load(&dpart[t+256], __ATOMIC_RELAXED, __HIP_MEMORY_SCOPE_AGENT)
               + ((t < NTRI-512)
                  ? __hip_atomic_load(&dpart[t+512], __ATOMIC_RELAXED, __HIP_MEMORY_SCOPE_AGENT)
                  : 0.0);
  double s_q2 = 0.0;
  #pragma unroll
  for (int i = t; i < NATOM; i += 256){ double q = (double)chg[i]; s_q2 += q*q; }
  #pragma unroll
  for (int off = 32; off > 0; off >>= 1){
    s_dir += __shfl_down(s_dir, off);
    s_q2  += __shfl_down(s_q2,  off);
  }
  if (lane == 0){ red[4+wid] = s_dir; red[8+wid] = s_q2; }
  __syncthreads();
  if (t == 0){
    double D = red[4]+red[5]+red[6]+red[7];
    double Q = red[8]+red[9]+red[10]+red[11];
    double R = __hip_atomic_load(acc_rec, __ATOMIC_ACQUIRE, __HIP_MEMORY_SCOPE_AGENT);
    // R includes f64-poison offset -3.7e-103: negligible
    double b00=box[0],b01=box[1],b02=box[2],
           b10=box[3],b11=box[4],b12=box[5],
           b20=box[6],b21=box[7],b22=box[8];
    double det = b00*(b11*b22 - b12*b21) - b01*(b10*b22 - b12*b20) + b02*(b10*b21 - b11*b20);
    double V = fabs(det);
    const double PI_D = 3.141592653589793238462643;
    double edir  = 0.5 * (double)COULOMB_F * D;
    double erec  = (double)COULOMB_F / (2.0*PI_D*V) * R;
    double eself = -(double)COULOMB_F * 4.985823141035867 / sqrt(PI_D) * Q;
    out[0] = (float)(edir - erec - eself);
  }
}

// ========== ONE fused kernel ==========
// blocks 0..543   : triangular direct tiles -> agent atomic store dpart[b] -> bump dctr
// blocks 544..671 : spread -> LDS mesh -> device-scope fold into grid -> bump sctr;
//                   the 128th folder runs the batched 16-mz DFT inline, adds to acc_rec,
//                   bumps dctr. Last of 545 dctr bumps runs final_combine.
// Counter-gated; no spins; correct under any dispatch order.
__global__ __launch_bounds__(256) void pme_kernel(const float* __restrict__ pos,
    const float* __restrict__ chg, const float* __restrict__ box,
    float* __restrict__ grid, double* __restrict__ dpart,
    double* __restrict__ acc_rec, unsigned* __restrict__ sctr,
    unsigned* __restrict__ dctr, float* __restrict__ out)
{
  __shared__ __align__(16) float sg[NGRID];   // spread mesh; recip Czall aliased here
  __shared__ float2 Cyall[8*KX*KY];           // [l][my*14+mx... y-pass out] 13.44 KB
  __shared__ float2 Tz[KZ*KZ];                // [mz][gz] 256
  __shared__ float2 Ty[KY*KY];                // [my][gy] 225
  __shared__ float2 Tx[KX*KX];                // [mx][gx] 196
  __shared__ float bmx[KX], bmy[KY], bmzt[KZ];
  __shared__ float4 sj[64];                   // direct j-tile (x,y,z,q)
  __shared__ double red[12];
  __shared__ int flag;
  int t = threadIdx.x;
  int b = blockIdx.x;

  if (b < NTRI){
    // -------- direct tile (ci,cj); off-diagonal tiles counted twice --------
    int rem = b, ci = 0;
    while (true){ int cnt = 64 - 4*ci; if (rem < cnt) break; rem -= cnt; ++ci; }
    int cj = 4*ci + rem;
    bool offdiag = (rem >= 4);
    int i  = ci*256 + t;
    int j0 = cj*64;
    if (t < 64){
      int j = j0 + t;
      sj[t] = make_float4(pos[j*3+0], pos[j*3+1], pos[j*3+2], chg[j]);
    }
    __syncthreads();

    float b00=box[0],b01=box[1],b02=box[2],
          b10=box[3],b11=box[4],b12=box[5],
          b20=box[6],b21=box[7],b22=box[8];
    bool diag = (b01==0.f && b02==0.f && b10==0.f && b12==0.f && b20==0.f && b21==0.f);
    float i00 = 1.f/b00, i11 = 1.f/b11, i22 = 1.f/b22;

    float xi = pos[i*3+0], yi = pos[i*3+1], zi = pos[i*3+2], qi = chg[i];
    const float A2 = ALPHA_F*ALPHA_F;
    float e = 0.f;

    if (diag){
      #pragma unroll 4
      for (int jj = 0; jj < 64; ++jj){
        float4 v = sj[jj];
        float dx = xi - v.x, dy = yi - v.y, dz = zi - v.z;
        dz -= b22*rintf(dz*i22);
        dy -= b11*rintf(dy*i11);
        dx -= b00*rintf(dx*i00);
        float r2 = dx*dx + dy*dy + dz*dz;
        // self-pair gives exactly r2==0 -> excluded by r2>0
        if (r2 < CUT2_F && r2 > 0.f){
          float rinv = __builtin_amdgcn_rsqf(r2);
          float x = ALPHA_F * (r2 * rinv);
          e += qi * v.w * erfc_poly(x) * __expf(-A2*r2) * rinv;
        }
      }
    } else {
      for (int jj = 0; jj < 64; ++jj){
        float4 v = sj[jj];
        float dx = xi - v.x, dy = yi - v.y, dz = zi - v.z;
        float t2 = rintf(dz * i22); dx -= b20*t2; dy -= b21*t2; dz -= b22*t2;
        float t1 = rintf(dy * i11); dx -= b10*t1; dy -= b11*t1; dz -= b12*t1;
        float t0 = rintf(dx * i00); dx -= b00*t0; dy -= b01*t0; dz -= b02*t0;
        float r2 = dx*dx + dy*dy + dz*dz;
        if (r2 < CUT2_F && r2 > 0.f){
          float rinv = __builtin_amdgcn_rsqf(r2);
          float x = ALPHA_F * (r2 * rinv);
          e += qi * v.w * erfc_poly(x) * __expf(-A2*r2) * rinv;
        }
      }
    }

    double de = (double)e;
    #pragma unroll
    for (int off = 32; off > 0; off >>= 1) de += __shfl_down(de, off);
    if ((t & 63) == 0) red[t >> 6] = de;
    __syncthreads();
    if (t == 0){
      double s = red[0]+red[1]+red[2]+red[3];
      s = offdiag ? 2.0*s : s;
      __hip_atomic_store(&dpart[b], s, __ATOMIC_RELAXED, __HIP_MEMORY_SCOPE_AGENT);
      asm volatile("s_waitcnt vmcnt(0)" ::: "memory");   // store retired before counter
      unsigned old = __hip_atomic_fetch_add(dctr, 1u, __ATOMIC_ACQ_REL, __HIP_MEMORY_SCOPE_AGENT);
      flag = (old == DONE_LAST) ? 1 : 0;
    }
    __syncthreads();
    if (flag) final_combine(t, chg, box, dpart, acc_rec, out, red);
    return;
  }

  // -------- spread: (atom,jx) split over 160 threads -> LDS mesh -> fold --------
  int sb = b - NTRI;
  for (int i = t; i < NGRID; i += 256) sg[i] = 0.f;
  __syncthreads();

  if (t < APB*5){
    int a   = t / 5;
    int jxi = t - 5*a;
    int atom = sb*APB + a;
    float bx[9], inv[9];
    #pragma unroll
    for (int i = 0; i < 9; ++i) bx[i] = box[i];
    inv3x3(bx, inv);

    float px = pos[atom*3+0], py = pos[atom*3+1], pz = pos[atom*3+2];
    float qi = chg[atom];
    float fr[3];
    fr[0] = px*inv[0] + py*inv[3] + pz*inv[6];
    fr[1] = px*inv[1] + py*inv[4] + pz*inv[7];
    fr[2] = px*inv[2] + py*inv[5] + pz*inv[8];

    const int Ks[3] = {KX, KY, KZ};
    float w[3][5]; int id[3][5];
    #pragma unroll
    for (int ax = 0; ax < 3; ++ax) {
      float f = fr[ax] - floorf(fr[ax]);
      float u = f * (float)Ks[ax];
      float bse = floorf(u);
      float x = u - bse;
      int bi = (int)bse;
      #pragma unroll
      for (int j = 0; j < 5; ++j) {
        w[ax][j] = M5f(x + (float)j);          // weight for grid point (base - j)
        int ii = bi - j; if (ii < 0) ii += Ks[ax];
        id[ax][j] = ii;
      }
    }
    float qx = qi * w[0][jxi];
    int ox = id[0][jxi]*SLAB;
    #pragma unroll
    for (int jy = 0; jy < 5; ++jy) {
      float qxy = qx * w[1][jy];
      int oxy = ox + id[1][jy]*KZ;
      #pragma unroll
      for (int jz = 0; jz < 5; ++jz)
        atomicAdd(&sg[oxy + id[2][jz]], qxy * w[2][jz]);
    }
  }
  __syncthreads();
  for (int i = t; i < NGRID; i += 256){
    float v = sg[i];
    if (v != 0.f) atomicAdd(&grid[i], v);      // device-scope fold into ONE mesh
  }
  __syncthreads();                              // all folds retired before counter
  if (t == 0){
    unsigned old = __hip_atomic_fetch_add(sctr, 1u, __ATOMIC_ACQ_REL, __HIP_MEMORY_SCOPE_AGENT);
    flag = (old == SPREAD_LAST) ? 1 : 0;
  }
  __syncthreads();
  if (!flag) return;

  // ======== recip (only the 128th-arriving spread block) — batched all-mz DFT ========
  // Czall[l][u] (l = mz within group of 8, u = gx*KY+gy) aliases the dead sg mesh.
  float2* Czall = (float2*)sg;        // 8*210 float2 = 13440 B, exact overlay

  // ---- twiddle + moduli tables ----
  {
    int mz = t >> 4, gz = t & 15;     // t < 256 covers all of Tz
    float s, c; __sincosf(-TWOPI_F*(float)((mz*gz)&15)/(float)KZ, &s, &c);
    Tz[t] = make_float2(c, s);
  }
  if (t < KY*KY){
    int my = t / KY, gy = t % KY;
    float s, c; __sincosf(-TWOPI_F*(float)((my*gy)%KY)/(float)KY, &s, &c);
    Ty[t] = make_float2(c, s);
  }
  if (t < KX*KX){
    int mx = t / KX, gx = t % KX;
    float s, c; __sincosf(-TWOPI_F*(float)((mx*gx)%KX)/(float)KX, &s, &c);
    Tx[t] = make_float2(c, s);
  }
  if (t < KX) bmx[t]  = bmod(t, KX);
  if (t < KY) bmy[t]  = bmod(t, KY);
  if (t < KZ) bmzt[t] = bmod(t, KZ);

  // ---- per-thread prep: z-column (u<210) + recip matrix (all threads) ----
  int u = t;
  float q[KZ];
  if (u < KX*KY){
    const float P = __uint_as_float(POIS32);    // grid cells = poison + folded sums
    #pragma unroll
    for (int k = 0; k < KZ; ++k)
      q[k] = __hip_atomic_load(&grid[u*KZ + k], __ATOMIC_RELAXED, __HIP_MEMORY_SCOPE_AGENT) - P;
  }
  float bxm[9], inv[9];
  #pragma unroll
  for (int k = 0; k < 9; ++k) bxm[k] = box[k];
  inv3x3(bxm, inv);
  __syncthreads();                    // tables ready

  double s_rec = 0.0;
  #pragma unroll
  for (int g = 0; g < 2; ++g){
    // ---- A: z-DFT, 8 mz per column, into Czall[l][u] ----
    if (u < KX*KY){
      #pragma unroll
      for (int l = 0; l < 8; ++l){
        int mz = g*8 + l;
        float br = 0.f, bi = 0.f;
        #pragma unroll
        for (int gz = 0; gz < KZ; ++gz){
          float2 w = Tz[mz*KZ + gz];
          br += q[gz]*w.x; bi += q[gz]*w.y;
        }
        Czall[l*(KX*KY) + u] = make_float2(br, bi);
      }
    }
    __syncthreads();
    // ---- B: y-pass, 1680 items (l,gx,my) -> Cyall[l][my*KX+gx] ----
    #pragma unroll
    for (int k = 0; k < 7; ++k){
      int w = t + 256*k;
      if (w < 8*KX*KY){
        int l = w / (KX*KY), v = w - l*(KX*KY);
        int gx = v / KY, my = v - gx*KY;
        float ar = 0.f, ai = 0.f;
        #pragma unroll
        for (int gy = 0; gy < KY; ++gy){
          float2 cz = Czall[l*(KX*KY) + gx*KY + gy];
          float2 ww = Ty[my*KY + gy];
          ar += cz.x*ww.x - cz.y*ww.y;
          ai += cz.x*ww.y + cz.y*ww.x;
        }
        Cyall[l*(KX*KY) + my*KX + gx] = make_float2(ar, ai);
      }
    }
    __syncthreads();
    // ---- C: x-pass + green, 1680 items (l,my,mx) ----
    #pragma unroll
    for (int k = 0; k < 7; ++k){
      int w = t + 256*k;
      if (w < 8*KX*KY){
        int l = w / (KX*KY), v = w - l*(KX*KY);
        int my = v / KX, mx = v - my*KX;
        int mz = g*8 + l;
        float Fr = 0.f, Fi = 0.f;
        #pragma unroll
        for (int gx = 0; gx < KX; ++gx){
          float2 cy = Cyall[l*(KX*KY) + my*KX + gx];
          float2 ww = Tx[mx*KX + gx];
          Fr += cy.x*ww.x - cy.y*ww.y;
          Fi += cy.x*ww.y + cy.y*ww.x;
        }
        float B = bmx[mx]*bmy[my]*bmzt[mz];
        float fx = (mx <= (KX-1)/2) ? (float)mx : (float)(mx - KX);
        float fy = (my <= (KY-1)/2) ? (float)my : (float)(my - KY);
        float fz = (mz <= (KZ-1)/2) ? (float)mz : (float)(mz - KZ);
        float m0 = fx*inv[0] + fy*inv[1] + fz*inv[2];
        float m1 = fx*inv[3] + fy*inv[4] + fz*inv[5];
        float m2c = fx*inv[6] + fy*inv[7] + fz*inv[8];
        float m2 = m0*m0 + m1*m1 + m2c*m2c;
        if (m2 > 0.f && B > 0.f){
          float green = __expf(-(PI_F*PI_F)*m2/(ALPHA_F*ALPHA_F)) / m2;
          s_rec += (double)(green*B) * ((double)Fr*(double)Fr + (double)Fi*(double)Fi);
        }
      }
    }
    // no barrier needed here: next group's A writes Czall (not read in C),
    // and the A->B barrier separates this C's Cyall reads from B's writes.
  }

  #pragma unroll
  for (int off = 32; off > 0; off >>= 1) s_rec += __shfl_down(s_rec, off);
  int lane = t & 63, wid = t >> 6;
  if (lane == 0) red[wid] = s_rec;
  __syncthreads();
  if (t == 0){
    atomicAdd(acc_rec, red[0]+red[1]+red[2]+red[3]);   // f64, device-scope
    asm volatile("s_waitcnt vmcnt(0)" ::: "memory");   // acc add retired before counter
    unsigned old = __hip_atomic_fetch_add(dctr, 1u, __ATOMIC_ACQ_REL, __HIP_MEMORY_SCOPE_AGENT);
    flag = (old == DONE_LAST) ? 1 : 0;
  }
  __syncthreads();
  if (flag) final_combine(t, chg, box, dpart, acc_rec, out, red);
}

extern "C" void kernel_launch(void* const* d_in, const int* in_sizes, int n_in,
                              void* d_out, int out_size, void* d_ws, size_t ws_size,
                              hipStream_t stream) {
  const float* pos = (const float*)d_in[0];   // [4096,3] f32
  const float* chg = (const float*)d_in[1];   // [4096]   f32
  const float* box = (const float*)d_in[2];   // [3,3]    f32
  float* out = (float*)d_out;

  // ws layout (all fields start at 0xAA poison; schemes account for it)
  char* w = (char*)d_ws;
  float*    grid    = (float*)w;                    // 3360 f32 @ 0 (16B aligned)
  double*   dpart   = (double*)(w + 16384);         // 544 f64 (agent atomic store/load)
  double*   acc_rec = (double*)(w + 24576);         // 1 f64 (starts -3.7e-103)
  unsigned* sctr    = (unsigned*)(w + 24584);       // spread counter, starts POIS32
  unsigned* dctr    = (unsigned*)(w + 24588);       // done counter,   starts POIS32

  pme_kernel<<<NTRI + NB, 256, 0, stream>>>(pos, chg, box, grid, dpart,
                                            acc_rec, sctr, dctr, out);
}